// Round 2
// baseline (863.943 us; speedup 1.0000x reference)
//
#include <hip/hip_runtime.h>
#include <hip/hip_bf16.h>
#include <math.h>

#define B_   256
#define NPG_ 200
#define N0_  (B_*NPG_)     // 51200
#define DEGC 16
#define E_   (N0_*DEGC)    // 819200
#define FIN_ 128
#define H_   256
#define K1_  100
#define K2_  50
#define K3_  25

// ---------------- fills / init ----------------
__global__ void fill_i32_k(int* p, int v, int n) {
    int i = blockIdx.x * 256 + threadIdx.x; if (i < n) p[i] = v;
}
__global__ void init_edges_k(const int* __restrict__ es, const int* __restrict__ ed,
                             int* __restrict__ src, int* __restrict__ dst, float* __restrict__ em) {
    int e = blockIdx.x * 256 + threadIdx.x;
    if (e < E_) { src[e] = es[e]; dst[e] = ed[e]; em[e] = 1.0f; }
}

// ---------------- tiled GEMM: C[n x FO] = A[n x K] @ W[K x FO] ----------------
__global__ void gemm64(const float* __restrict__ A, const float* __restrict__ W,
                       float* __restrict__ C, int n, int K, int FO) {
    __shared__ float As[16][65];
    __shared__ float Bs[16][65];
    int tid = threadIdx.x;
    int tx = tid & 15, ty = tid >> 4;
    int bm = blockIdx.x * 64, bn = blockIdx.y * 64;
    float acc[4][4] = {};
    for (int k0 = 0; k0 < K; k0 += 16) {
        #pragma unroll
        for (int i = 0; i < 4; i++) {
            int lin = i * 256 + tid;
            int r = lin >> 4, kk = lin & 15;
            As[kk][r] = A[(size_t)(bm + r) * K + k0 + kk];
        }
        #pragma unroll
        for (int i = 0; i < 4; i++) {
            int lin = i * 256 + tid;
            int nn = lin & 63, kk = lin >> 6;
            Bs[kk][nn] = W[(size_t)(k0 + kk) * FO + bn + nn];
        }
        __syncthreads();
        #pragma unroll
        for (int kk = 0; kk < 16; kk++) {
            float a[4], b[4];
            #pragma unroll
            for (int i = 0; i < 4; i++) a[i] = As[kk][ty * 4 + i];
            #pragma unroll
            for (int j = 0; j < 4; j++) b[j] = Bs[kk][tx * 4 + j];
            #pragma unroll
            for (int i = 0; i < 4; i++)
                #pragma unroll
                for (int j = 0; j < 4; j++) acc[i][j] += a[i] * b[j];
        }
        __syncthreads();
    }
    for (int i = 0; i < 4; i++)
        for (int j = 0; j < 4; j++)
            C[(size_t)(bm + ty * 4 + i) * FO + bn + tx * 4 + j] = acc[i][j];
}

// ---------------- degree + CSR ----------------
__global__ void deg_count_k(const int* __restrict__ dst, const float* __restrict__ em,
                            int* __restrict__ cnt) {
    int e = blockIdx.x * 256 + threadIdx.x; if (e >= E_) return;
    if (em[e] > 0.5f) atomicAdd(&cnt[dst[e]], 1);
}
__global__ void dinv_k(const int* __restrict__ cnt, float* __restrict__ dinv, int n) {
    int i = blockIdx.x * 256 + threadIdx.x; if (i >= n) return;
    dinv[i] = rsqrtf((float)cnt[i] + 1.0f);
}
__global__ void scan1_k(const int* __restrict__ cnt, int* __restrict__ off, int* __restrict__ bsum) {
    __shared__ int s[256];
    int t = threadIdx.x, i = blockIdx.x * 256 + t;
    int v = cnt[i];
    s[t] = v; __syncthreads();
    for (int d = 1; d < 256; d <<= 1) {
        int u = (t >= d) ? s[t - d] : 0;
        __syncthreads();
        s[t] += u;
        __syncthreads();
    }
    off[i] = s[t] - v;
    if (t == 255) bsum[blockIdx.x] = s[255];
}
__global__ void scan2_k(const int* __restrict__ bsum, int* __restrict__ bsumx, int nb, int* offEnd) {
    __shared__ int s[256];
    int t = threadIdx.x;
    s[t] = (t < nb) ? bsum[t] : 0;
    __syncthreads();
    if (t == 0) {
        int run = 0;
        for (int i = 0; i < nb; i++) { int v = s[i]; s[i] = run; run += v; }
        *offEnd = run;
    }
    __syncthreads();
    if (t < nb) bsumx[t] = s[t];
}
__global__ void scan3_k(int* __restrict__ off, int* __restrict__ pos, const int* __restrict__ bsumx, int n) {
    int i = blockIdx.x * 256 + threadIdx.x; if (i >= n) return;
    int v = off[i] + bsumx[blockIdx.x];
    off[i] = v; pos[i] = v;
}
__global__ void scatter_k(const int* __restrict__ dst, const float* __restrict__ em,
                          int* __restrict__ pos, int* __restrict__ eid) {
    int e = blockIdx.x * 256 + threadIdx.x; if (e >= E_) return;
    if (em[e] > 0.5f) { int p = atomicAdd(&pos[dst[e]], 1); eid[p] = e; }
}

// ---------------- GCN aggregation (wave per node, float4 features) ----------------
__global__ void agg_gcn_k(const float* __restrict__ xw, const int* __restrict__ src,
                          const int* __restrict__ off, const int* __restrict__ eid,
                          const float* __restrict__ dinv, const float* __restrict__ bias,
                          float* __restrict__ out, int n, int relu) {
    int node = blockIdx.x * 4 + (threadIdx.x >> 6);
    if (node >= n) return;
    int lane = threadIdx.x & 63;
    const float4* xw4 = (const float4*)xw;
    float dd = dinv[node];
    float4 acc = {0.f, 0.f, 0.f, 0.f};
    int e0 = off[node], e1 = off[node + 1];
    for (int j = e0; j < e1; j++) {
        int e = eid[j];
        int s = src[e];
        float c = dinv[s] * dd;
        float4 v = xw4[(size_t)s * 64 + lane];
        acc.x += c * v.x; acc.y += c * v.y; acc.z += c * v.z; acc.w += c * v.w;
    }
    float4 self = xw4[(size_t)node * 64 + lane];
    float sc = dd * dd;
    float4 r;
    r.x = acc.x + self.x * sc + bias[lane * 4 + 0];
    r.y = acc.y + self.y * sc + bias[lane * 4 + 1];
    r.z = acc.z + self.z * sc + bias[lane * 4 + 2];
    r.w = acc.w + self.w * sc + bias[lane * 4 + 3];
    if (relu) {
        r.x = fmaxf(r.x, 0.f); r.y = fmaxf(r.y, 0.f);
        r.z = fmaxf(r.z, 0.f); r.w = fmaxf(r.w, 0.f);
    }
    ((float4*)out)[(size_t)node * 64 + lane] = r;
}

// ---------------- score: xs = h @ Ws (wave-per-node dot) ----------------
__global__ void node_dot_k(const float* __restrict__ h, const float* __restrict__ Ws,
                           float* __restrict__ xs, int n) {
    int node = blockIdx.x * 4 + (threadIdx.x >> 6);
    if (node >= n) return;
    int lane = threadIdx.x & 63;
    const float4* h4 = (const float4*)h;
    float4 v = h4[(size_t)node * 64 + lane];
    float p = v.x * Ws[lane * 4 + 0] + v.y * Ws[lane * 4 + 1] +
              v.z * Ws[lane * 4 + 2] + v.w * Ws[lane * 4 + 3];
    for (int d = 32; d > 0; d >>= 1) p += __shfl_down(p, d);
    if (lane == 0) xs[node] = p;
}
__global__ void score_edge_k(const float* __restrict__ xs, const int* __restrict__ src,
                             const int* __restrict__ off, const int* __restrict__ eid,
                             const float* __restrict__ dinv, const float* __restrict__ bs,
                             float* __restrict__ score, int n) {
    int i = blockIdx.x * 256 + threadIdx.x; if (i >= n) return;
    float dd = dinv[i];
    float acc = 0.f;
    for (int j = off[i]; j < off[i + 1]; j++) {
        int e = eid[j]; int s = src[e];
        acc += dinv[s] * dd * xs[s];
    }
    score[i] = acc + xs[i] * dd * dd + bs[0];
}

// ---------------- per-graph bitonic top-k ----------------
__global__ void topk_k(const float* __restrict__ score, int npg, int k,
                       int* __restrict__ perm, int* __restrict__ remap) {
    __shared__ float sc[256];
    __shared__ int   id[256];
    int g = blockIdx.x, t = threadIdx.x;
    sc[t] = (t < npg) ? score[g * npg + t] : -INFINITY;
    id[t] = (t < npg) ? t : 0x7fffffff;
    __syncthreads();
    for (int ksz = 2; ksz <= 256; ksz <<= 1) {
        for (int j = ksz >> 1; j > 0; j >>= 1) {
            int ixj = t ^ j;
            if (ixj > t) {
                float s1 = sc[t], s2 = sc[ixj];
                int i1 = id[t], i2 = id[ixj];
                bool asc = ((t & ksz) == 0);
                // sort key = (-score, idx) ascending -> score desc, idx asc (jax tie-break)
                bool agtb = (s1 < s2) || (s1 == s2 && i1 > i2);
                if (asc ? agtb : !agtb) { sc[t] = s2; sc[ixj] = s1; id[t] = i2; id[ixj] = i1; }
            }
            __syncthreads();
        }
    }
    if (t < k) {
        int gi = g * npg + id[t];
        int nj = g * k + t;
        perm[nj] = gi;
        remap[gi] = nj;
    }
}

// ---------------- pool (gather + tanh gate) ----------------
__global__ void pool_k(const float* __restrict__ h, const float* __restrict__ score,
                       const int* __restrict__ perm, float* __restrict__ out, int nNew) {
    int j = blockIdx.x * 4 + (threadIdx.x >> 6);
    if (j >= nNew) return;
    int lane = threadIdx.x & 63;
    int p = perm[j];
    float t = tanhf(score[p]);
    float4 v = ((const float4*)h)[(size_t)p * 64 + lane];
    v.x *= t; v.y *= t; v.z *= t; v.w *= t;
    ((float4*)out)[(size_t)j * 64 + lane] = v;
}

// ---------------- edge remap ----------------
__global__ void edge_remap_k(int* __restrict__ src, int* __restrict__ dst,
                             float* __restrict__ em, const int* __restrict__ remap) {
    int e = blockIdx.x * 256 + threadIdx.x; if (e >= E_) return;
    int ns = remap[src[e]], nd = remap[dst[e]];
    float v = em[e];
    em[e] = (v > 0.5f && ns >= 0 && nd >= 0) ? 1.0f : 0.0f;
    src[e] = ns < 0 ? 0 : ns;
    dst[e] = nd < 0 ? 0 : nd;
}

// ---------------- readout: gmp || gap, accumulate into z ----------------
__global__ void readout_k(const float* __restrict__ x, float* __restrict__ z, int k, int accumulate) {
    int g = blockIdx.x, f = threadIdx.x;   // 256 threads = H
    float mx = -INFINITY, sm = 0.f;
    for (int r = 0; r < k; r++) {
        float v = x[(size_t)(g * k + r) * H_ + f];
        mx = fmaxf(mx, v); sm += v;
    }
    float mean = sm / (float)k;
    if (accumulate) { z[g * 512 + f] += mx; z[g * 512 + 256 + f] += mean; }
    else            { z[g * 512 + f]  = mx; z[g * 512 + 256 + f]  = mean; }
}

// ---------------- small MLP GEMM ----------------
__global__ void mlp_gemm_k(const float* __restrict__ A, const float* __restrict__ W,
                           const float* __restrict__ bias, float* __restrict__ C,
                           int M, int K, int N, int relu) {
    int idx = blockIdx.x * 256 + threadIdx.x;
    if (idx >= M * N) return;
    int m = idx / N, n = idx % N;
    float acc = bias[n];
    for (int k = 0; k < K; k++) acc += A[m * K + k] * W[k * N + n];
    if (relu) acc = fmaxf(acc, 0.f);
    C[idx] = acc;
}

__global__ void logsoftmax_k(const float* __restrict__ z, float* __restrict__ out) {
    int m = blockIdx.x * 256 + threadIdx.x;
    if (m >= B_) return;
    float v[10]; float mx = -INFINITY;
    #pragma unroll
    for (int c = 0; c < 10; c++) { v[c] = z[m * 10 + c]; mx = fmaxf(mx, v[c]); }
    float s = 0.f;
    #pragma unroll
    for (int c = 0; c < 10; c++) s += expf(v[c] - mx);
    float ls = logf(s);
    #pragma unroll
    for (int c = 0; c < 10; c++) out[m * 10 + c] = v[c] - mx - ls;
}

extern "C" void kernel_launch(void* const* d_in, const int* in_sizes, int n_in,
                              void* d_out, int out_size, void* d_ws, size_t ws_size,
                              hipStream_t stream) {
    const float* x   = (const float*)d_in[0];
    const int*  esrc = (const int*) d_in[1];
    const int*  edst = (const int*) d_in[2];
    const float *W1 = (const float*)d_in[3],  *b1 = (const float*)d_in[4];
    const float *Ws1= (const float*)d_in[5],  *bs1= (const float*)d_in[6];
    const float *W2 = (const float*)d_in[7],  *b2 = (const float*)d_in[8];
    const float *Ws2= (const float*)d_in[9],  *bs2= (const float*)d_in[10];
    const float *W3 = (const float*)d_in[11], *b3 = (const float*)d_in[12];
    const float *Ws3= (const float*)d_in[13], *bs3= (const float*)d_in[14];
    const float *Wl1= (const float*)d_in[15], *bl1= (const float*)d_in[16];
    const float *Wl2= (const float*)d_in[17], *bl2= (const float*)d_in[18];
    const float *Wl3= (const float*)d_in[19], *bl3= (const float*)d_in[20];
    float* out = (float*)d_out;

    // ---- workspace layout (all 4-byte elems; ~146 MB total) ----
    float* ws = (float*)d_ws;
    float* XW   = ws;                        // N0*H
    float* Hb   = XW + (size_t)N0_ * H_;     // N0*H
    float* PH   = Hb + (size_t)N0_ * H_;     // (B*K1)*H
    float* DINV = PH + (size_t)B_ * K1_ * H_;// N0
    float* XS   = DINV + N0_;                // N0
    float* SCOR = XS + N0_;                  // N0
    float* EMF  = SCOR + N0_;                // E
    int*   SRC  = (int*)(EMF + E_);          // E
    int*   DST  = SRC + E_;                  // E
    int*   CNT  = DST + E_;                  // N0+1
    int*   OFF  = CNT + (N0_ + 1);           // N0+1
    int*   POS  = OFF + (N0_ + 1);           // N0
    int*   BSUM = POS + N0_;                 // 256
    int*   BSX  = BSUM + 256;                // 256
    int*   EID  = BSX + 256;                 // E
    int*   PERM = EID + E_;                  // B*K1
    int*   REMAP= PERM + B_ * K1_;           // N0
    float* Z    = (float*)(REMAP + N0_);     // B*512
    float* Z1   = Z + B_ * 512;              // B*256
    float* Z2   = Z1 + B_ * 256;             // B*128
    float* Z3   = Z2 + B_ * 128;             // B*10

    auto cdiv = [](int a, int b) { return (a + b - 1) / b; };
    const int EB = E_ / 256;   // 3200

    // ---- stage setup: copy edges, em=1 ----
    init_edges_k<<<EB, 256, 0, stream>>>(esrc, edst, SRC, DST, EMF);

    const int nodes[4] = { N0_, B_ * K1_, B_ * K2_, B_ * K3_ };
    const int npgs[3]  = { NPG_, K1_, K2_ };
    const int ks[3]    = { K1_, K2_, K3_ };
    const float* Wm[3]  = { W1, W2, W3 };
    const float* bm[3]  = { b1, b2, b3 };
    const float* Wsm[3] = { Ws1, Ws2, Ws3 };
    const float* bsm[3] = { bs1, bs2, bs3 };

    for (int st = 0; st < 3; st++) {
        int n = nodes[st];
        int nNew = nodes[st + 1];
        int npg = npgs[st], k = ks[st];
        int nb = n / 256;                       // n is a multiple of 256 at every stage

        // 1. xw = X @ W
        if (st == 0)
            gemm64<<<dim3(n / 64, H_ / 64), 256, 0, stream>>>(x, Wm[st], XW, n, FIN_, H_);
        else
            gemm64<<<dim3(n / 64, H_ / 64), 256, 0, stream>>>(PH, Wm[st], XW, n, H_, H_);

        // 2. degree counts + CSR
        fill_i32_k<<<cdiv(n, 256), 256, 0, stream>>>(CNT, 0, n);
        deg_count_k<<<EB, 256, 0, stream>>>(DST, EMF, CNT);
        dinv_k<<<cdiv(n, 256), 256, 0, stream>>>(CNT, DINV, n);
        scan1_k<<<nb, 256, 0, stream>>>(CNT, OFF, BSUM);
        scan2_k<<<1, 256, 0, stream>>>(BSUM, BSX, nb, OFF + n);
        scan3_k<<<nb, 256, 0, stream>>>(OFF, POS, BSX, n);
        scatter_k<<<EB, 256, 0, stream>>>(DST, EMF, POS, EID);

        // 3. h = relu(agg + self + b)
        agg_gcn_k<<<n / 4, 256, 0, stream>>>(XW, SRC, OFF, EID, DINV, bm[st], Hb, n, 1);

        // 4. score GCN (same graph): xs = h @ Ws ; score = agg(xs) + self + bs
        node_dot_k<<<n / 4, 256, 0, stream>>>(Hb, Wsm[st], XS, n);
        score_edge_k<<<cdiv(n, 256), 256, 0, stream>>>(XS, SRC, OFF, EID, DINV, bsm[st], SCOR, n);

        // 5. top-k per graph -> perm, remap
        fill_i32_k<<<cdiv(n, 256), 256, 0, stream>>>(REMAP, -1, n);
        topk_k<<<B_, 256, 0, stream>>>(SCOR, npg, k, PERM, REMAP);

        // 6. pooled x = h[perm] * tanh(score[perm])
        pool_k<<<nNew / 4, 256, 0, stream>>>(Hb, SCOR, PERM, PH, nNew);

        // 7. readout (accumulate z across stages)
        readout_k<<<B_, 256, 0, stream>>>(PH, Z, k, st > 0 ? 1 : 0);

        // 8. remap edges for next stage
        edge_remap_k<<<EB, 256, 0, stream>>>(SRC, DST, EMF, REMAP);
    }

    // ---- MLP head ----
    mlp_gemm_k<<<cdiv(B_ * 256, 256), 256, 0, stream>>>(Z,  Wl1, bl1, Z1, B_, 512, 256, 1);
    mlp_gemm_k<<<cdiv(B_ * 128, 256), 256, 0, stream>>>(Z1, Wl2, bl2, Z2, B_, 256, 128, 1);
    mlp_gemm_k<<<cdiv(B_ * 10, 256), 256, 0, stream>>>(Z2, Wl3, bl3, Z3, B_, 128, 10, 0);
    logsoftmax_k<<<1, 256, 0, stream>>>(Z3, out);
}

// Round 3
// 578.940 us; speedup vs baseline: 1.4923x; 1.4923x over previous
//
#include <hip/hip_runtime.h>
#include <hip/hip_bf16.h>
#include <math.h>

#define B_   256
#define NPG_ 200
#define N0_  (B_*NPG_)     // 51200
#define DEGC 16
#define E_   (N0_*DEGC)    // 819200
#define FIN_ 128
#define H_   256
#define K1_  100
#define K2_  50
#define K3_  25

// ---------------- init: copy edges, em=1, zero CNT for stage 0 ----------------
__global__ void init_edges_k(const int* __restrict__ es, const int* __restrict__ ed,
                             int* __restrict__ src, int* __restrict__ dst,
                             float* __restrict__ em, int* __restrict__ cnt) {
    int e = blockIdx.x * 256 + threadIdx.x;
    if (e < E_) { src[e] = es[e]; dst[e] = ed[e]; em[e] = 1.0f; }
    if (e < N0_) cnt[e] = 0;
}

// ---------------- gemm128: C[n x FO] = A[n x K] @ W[K x FO], 128x128 tile ----------------
__global__ __launch_bounds__(256) void gemm128(const float* __restrict__ A, const float* __restrict__ W,
                        float* __restrict__ C, int n, int K, int FO) {
    __shared__ float As[16][132];
    __shared__ float Bs[16][132];
    int t = threadIdx.x;
    int tx = t & 15, ty = t >> 4;
    int bm = blockIdx.x * 128, bn = blockIdx.y * 128;
    int ar = t >> 1, akq = (t & 1) * 8;          // A staging: row, k-offset
    int bkk = t >> 4, bn0 = (t & 15) * 8;        // B staging: k, n-offset
    float acc[8][8] = {};
    for (int k0 = 0; k0 < K; k0 += 16) {
        float4 a0 = *(const float4*)&A[(size_t)(bm + ar) * K + k0 + akq];
        float4 a1 = *(const float4*)&A[(size_t)(bm + ar) * K + k0 + akq + 4];
        As[akq + 0][ar] = a0.x; As[akq + 1][ar] = a0.y; As[akq + 2][ar] = a0.z; As[akq + 3][ar] = a0.w;
        As[akq + 4][ar] = a1.x; As[akq + 5][ar] = a1.y; As[akq + 6][ar] = a1.z; As[akq + 7][ar] = a1.w;
        *(float4*)&Bs[bkk][bn0]     = *(const float4*)&W[(size_t)(k0 + bkk) * FO + bn + bn0];
        *(float4*)&Bs[bkk][bn0 + 4] = *(const float4*)&W[(size_t)(k0 + bkk) * FO + bn + bn0 + 4];
        __syncthreads();
        #pragma unroll
        for (int kk = 0; kk < 16; kk++) {
            float4 av0 = *(float4*)&As[kk][ty * 8];
            float4 av1 = *(float4*)&As[kk][ty * 8 + 4];
            float4 bv0 = *(float4*)&Bs[kk][tx * 8];
            float4 bv1 = *(float4*)&Bs[kk][tx * 8 + 4];
            float a[8] = {av0.x, av0.y, av0.z, av0.w, av1.x, av1.y, av1.z, av1.w};
            float b[8] = {bv0.x, bv0.y, bv0.z, bv0.w, bv1.x, bv1.y, bv1.z, bv1.w};
            #pragma unroll
            for (int i = 0; i < 8; i++)
                #pragma unroll
                for (int j = 0; j < 8; j++) acc[i][j] += a[i] * b[j];
        }
        __syncthreads();
    }
    #pragma unroll
    for (int i = 0; i < 8; i++) {
        float4 c0 = {acc[i][0], acc[i][1], acc[i][2], acc[i][3]};
        float4 c1 = {acc[i][4], acc[i][5], acc[i][6], acc[i][7]};
        *(float4*)&C[(size_t)(bm + ty * 8 + i) * FO + bn + tx * 8]     = c0;
        *(float4*)&C[(size_t)(bm + ty * 8 + i) * FO + bn + tx * 8 + 4] = c1;
    }
}

// ---------------- gemm64 (with optional bias+relu) for the small MLP layers ----------------
__global__ void gemm64(const float* __restrict__ A, const float* __restrict__ W,
                       const float* __restrict__ bias, float* __restrict__ C,
                       int n, int K, int FO, int relu) {
    __shared__ float As[16][65];
    __shared__ float Bs[16][65];
    int tid = threadIdx.x;
    int tx = tid & 15, ty = tid >> 4;
    int bm = blockIdx.x * 64, bn = blockIdx.y * 64;
    float acc[4][4] = {};
    for (int k0 = 0; k0 < K; k0 += 16) {
        #pragma unroll
        for (int i = 0; i < 4; i++) {
            int lin = i * 256 + tid;
            int r = lin >> 4, kk = lin & 15;
            As[kk][r] = A[(size_t)(bm + r) * K + k0 + kk];
        }
        #pragma unroll
        for (int i = 0; i < 4; i++) {
            int lin = i * 256 + tid;
            int nn = lin & 63, kk = lin >> 6;
            Bs[kk][nn] = W[(size_t)(k0 + kk) * FO + bn + nn];
        }
        __syncthreads();
        #pragma unroll
        for (int kk = 0; kk < 16; kk++) {
            float a[4], b[4];
            #pragma unroll
            for (int i = 0; i < 4; i++) a[i] = As[kk][ty * 4 + i];
            #pragma unroll
            for (int j = 0; j < 4; j++) b[j] = Bs[kk][tx * 4 + j];
            #pragma unroll
            for (int i = 0; i < 4; i++)
                #pragma unroll
                for (int j = 0; j < 4; j++) acc[i][j] += a[i] * b[j];
        }
        __syncthreads();
    }
    for (int i = 0; i < 4; i++)
        for (int j = 0; j < 4; j++) {
            float v = acc[i][j] + (bias ? bias[bn + tx * 4 + j] : 0.0f);
            if (relu) v = fmaxf(v, 0.0f);
            C[(size_t)(bm + ty * 4 + i) * FO + bn + tx * 4 + j] = v;
        }
}

// ---------------- degree + CSR ----------------
__global__ void deg_count_k(const int* __restrict__ dst, const float* __restrict__ em,
                            int* __restrict__ cnt) {
    int e = blockIdx.x * 256 + threadIdx.x; if (e >= E_) return;
    if (em[e] > 0.5f) atomicAdd(&cnt[dst[e]], 1);
}
__global__ void scan1_k(const int* __restrict__ cnt, int* __restrict__ off,
                        int* __restrict__ bsum, float* __restrict__ dinv) {
    __shared__ int s[256];
    int t = threadIdx.x, i = blockIdx.x * 256 + t;
    int v = cnt[i];
    dinv[i] = rsqrtf((float)v + 1.0f);
    s[t] = v; __syncthreads();
    for (int d = 1; d < 256; d <<= 1) {
        int u = (t >= d) ? s[t - d] : 0;
        __syncthreads();
        s[t] += u;
        __syncthreads();
    }
    off[i] = s[t] - v;
    if (t == 255) bsum[blockIdx.x] = s[255];
}
__global__ void scan2_k(const int* __restrict__ bsum, int* __restrict__ bsumx, int nb, int* offEnd) {
    __shared__ int s[256];
    int t = threadIdx.x;
    s[t] = (t < nb) ? bsum[t] : 0;
    __syncthreads();
    if (t == 0) {
        int run = 0;
        for (int i = 0; i < nb; i++) { int v = s[i]; s[i] = run; run += v; }
        *offEnd = run;
    }
    __syncthreads();
    if (t < nb) bsumx[t] = s[t];
}
__global__ void scan3_k(int* __restrict__ off, int* __restrict__ pos, const int* __restrict__ bsumx,
                        int* __restrict__ remap, int n) {
    int i = blockIdx.x * 256 + threadIdx.x; if (i >= n) return;
    int v = off[i] + bsumx[blockIdx.x];
    off[i] = v; pos[i] = v;
    remap[i] = -1;
}
// scatter CSR-ordered SOURCE ids directly (kills one indirection in agg/score)
__global__ void scatter_k(const int* __restrict__ src, const int* __restrict__ dst,
                          const float* __restrict__ em, int* __restrict__ pos,
                          int* __restrict__ csrc) {
    int e = blockIdx.x * 256 + threadIdx.x; if (e >= E_) return;
    if (em[e] > 0.5f) { int p = atomicAdd(&pos[dst[e]], 1); csrc[p] = src[e]; }
}

// ---------------- GCN aggregation (wave per node, float4 features) ----------------
__global__ void agg_gcn_k(const float* __restrict__ xw, const int* __restrict__ off,
                          const int* __restrict__ csrc, const float* __restrict__ dinv,
                          const float* __restrict__ bias, float* __restrict__ out, int n, int relu) {
    int node = blockIdx.x * 4 + (threadIdx.x >> 6);
    if (node >= n) return;
    int lane = threadIdx.x & 63;
    const float4* xw4 = (const float4*)xw;
    float dd = dinv[node];
    float4 acc = {0.f, 0.f, 0.f, 0.f};
    int e0 = off[node], e1 = off[node + 1];
    for (int j = e0; j < e1; j++) {
        int s = csrc[j];
        float c = dinv[s] * dd;
        float4 v = xw4[(size_t)s * 64 + lane];
        acc.x += c * v.x; acc.y += c * v.y; acc.z += c * v.z; acc.w += c * v.w;
    }
    float4 self = xw4[(size_t)node * 64 + lane];
    float sc = dd * dd;
    float4 r;
    r.x = acc.x + self.x * sc + bias[lane * 4 + 0];
    r.y = acc.y + self.y * sc + bias[lane * 4 + 1];
    r.z = acc.z + self.z * sc + bias[lane * 4 + 2];
    r.w = acc.w + self.w * sc + bias[lane * 4 + 3];
    if (relu) {
        r.x = fmaxf(r.x, 0.f); r.y = fmaxf(r.y, 0.f);
        r.z = fmaxf(r.z, 0.f); r.w = fmaxf(r.w, 0.f);
    }
    ((float4*)out)[(size_t)node * 64 + lane] = r;
}

// ---------------- score: xs = h @ Ws (wave-per-node dot) ----------------
__global__ void node_dot_k(const float* __restrict__ h, const float* __restrict__ Ws,
                           float* __restrict__ xs, int n) {
    int node = blockIdx.x * 4 + (threadIdx.x >> 6);
    if (node >= n) return;
    int lane = threadIdx.x & 63;
    const float4* h4 = (const float4*)h;
    float4 v = h4[(size_t)node * 64 + lane];
    float p = v.x * Ws[lane * 4 + 0] + v.y * Ws[lane * 4 + 1] +
              v.z * Ws[lane * 4 + 2] + v.w * Ws[lane * 4 + 3];
    for (int d = 32; d > 0; d >>= 1) p += __shfl_down(p, d);
    if (lane == 0) xs[node] = p;
}
__global__ void score_edge_k(const float* __restrict__ xs, const int* __restrict__ off,
                             const int* __restrict__ csrc, const float* __restrict__ dinv,
                             const float* __restrict__ bs, float* __restrict__ score, int n) {
    int i = blockIdx.x * 256 + threadIdx.x; if (i >= n) return;
    float dd = dinv[i];
    float acc = 0.f;
    for (int j = off[i]; j < off[i + 1]; j++) {
        int s = csrc[j];
        acc += dinv[s] * dd * xs[s];
    }
    score[i] = acc + xs[i] * dd * dd + bs[0];
}

// ---------------- per-graph bitonic top-k ----------------
__global__ void topk_k(const float* __restrict__ score, int npg, int k,
                       int* __restrict__ perm, int* __restrict__ remap) {
    __shared__ float sc[256];
    __shared__ int   id[256];
    int g = blockIdx.x, t = threadIdx.x;
    sc[t] = (t < npg) ? score[g * npg + t] : -INFINITY;
    id[t] = (t < npg) ? t : 0x7fffffff;
    __syncthreads();
    for (int ksz = 2; ksz <= 256; ksz <<= 1) {
        for (int j = ksz >> 1; j > 0; j >>= 1) {
            int ixj = t ^ j;
            if (ixj > t) {
                float s1 = sc[t], s2 = sc[ixj];
                int i1 = id[t], i2 = id[ixj];
                bool asc = ((t & ksz) == 0);
                bool agtb = (s1 < s2) || (s1 == s2 && i1 > i2);
                if (asc ? agtb : !agtb) { sc[t] = s2; sc[ixj] = s1; id[t] = i2; id[ixj] = i1; }
            }
            __syncthreads();
        }
    }
    if (t < k) {
        int gi = g * npg + id[t];
        int nj = g * k + t;
        perm[nj] = gi;
        remap[gi] = nj;
    }
}

// ---------------- fused pool (gather + tanh gate) + readout (gmp||gap) ----------------
__global__ void poolreadout_k(const float* __restrict__ h, const float* __restrict__ score,
                              const int* __restrict__ perm, float* __restrict__ ph,
                              float* __restrict__ z, int k, int accumulate) {
    __shared__ int   ps[128];
    __shared__ float ts[128];
    int g = blockIdx.x, f = threadIdx.x;     // 256 threads = H features
    if (f < k) {
        int p = perm[g * k + f];
        ps[f] = p;
        ts[f] = tanhf(score[p]);
    }
    __syncthreads();
    float mx = -INFINITY, sm = 0.f;
    for (int j = 0; j < k; j++) {
        float v = h[(size_t)ps[j] * H_ + f] * ts[j];
        ph[(size_t)(g * k + j) * H_ + f] = v;
        mx = fmaxf(mx, v); sm += v;
    }
    float mean = sm / (float)k;
    if (accumulate) { z[g * 512 + f] += mx; z[g * 512 + 256 + f] += mean; }
    else            { z[g * 512 + f]  = mx; z[g * 512 + 256 + f]  = mean; }
}

// ---------------- edge remap (also zeroes CNT for next stage) ----------------
__global__ void edge_remap_k(int* __restrict__ src, int* __restrict__ dst,
                             float* __restrict__ em, const int* __restrict__ remap,
                             int* __restrict__ cnt, int nNext) {
    int e = blockIdx.x * 256 + threadIdx.x; if (e >= E_) return;
    int ns = remap[src[e]], nd = remap[dst[e]];
    float v = em[e];
    em[e] = (v > 0.5f && ns >= 0 && nd >= 0) ? 1.0f : 0.0f;
    src[e] = ns < 0 ? 0 : ns;
    dst[e] = nd < 0 ? 0 : nd;
    if (e < nNext) cnt[e] = 0;
}

// ---------------- fused MLP layer-3 + log_softmax: one 64-lane block per row ----------------
__global__ void mlp3_lsm_k(const float* __restrict__ A, const float* __restrict__ W,
                           const float* __restrict__ bias, float* __restrict__ out) {
    int m = blockIdx.x, l = threadIdx.x;   // 64 lanes, K=128
    float a0 = A[m * 128 + l], a1 = A[m * 128 + 64 + l];
    float r[10];
    #pragma unroll
    for (int n = 0; n < 10; n++) r[n] = a0 * W[l * 10 + n] + a1 * W[(l + 64) * 10 + n];
    #pragma unroll
    for (int d = 1; d < 64; d <<= 1)
        #pragma unroll
        for (int n = 0; n < 10; n++) r[n] += __shfl_xor(r[n], d);
    float v[10]; float mx = -INFINITY;
    #pragma unroll
    for (int n = 0; n < 10; n++) { v[n] = r[n] + bias[n]; mx = fmaxf(mx, v[n]); }
    float s = 0.f;
    #pragma unroll
    for (int n = 0; n < 10; n++) s += expf(v[n] - mx);
    float ls = logf(s);
    if (l < 10) out[m * 10 + l] = v[l] - mx - ls;
}

extern "C" void kernel_launch(void* const* d_in, const int* in_sizes, int n_in,
                              void* d_out, int out_size, void* d_ws, size_t ws_size,
                              hipStream_t stream) {
    const float* x   = (const float*)d_in[0];
    const int*  esrc = (const int*) d_in[1];
    const int*  edst = (const int*) d_in[2];
    const float *W1 = (const float*)d_in[3],  *b1 = (const float*)d_in[4];
    const float *Ws1= (const float*)d_in[5],  *bs1= (const float*)d_in[6];
    const float *W2 = (const float*)d_in[7],  *b2 = (const float*)d_in[8];
    const float *Ws2= (const float*)d_in[9],  *bs2= (const float*)d_in[10];
    const float *W3 = (const float*)d_in[11], *b3 = (const float*)d_in[12];
    const float *Ws3= (const float*)d_in[13], *bs3= (const float*)d_in[14];
    const float *Wl1= (const float*)d_in[15], *bl1= (const float*)d_in[16];
    const float *Wl2= (const float*)d_in[17], *bl2= (const float*)d_in[18];
    const float *Wl3= (const float*)d_in[19], *bl3= (const float*)d_in[20];
    float* out = (float*)d_out;

    // ---- workspace layout ----
    float* ws = (float*)d_ws;
    float* XW   = ws;                        // N0*H
    float* Hb   = XW + (size_t)N0_ * H_;     // N0*H
    float* PH   = Hb + (size_t)N0_ * H_;     // (B*K1)*H
    float* DINV = PH + (size_t)B_ * K1_ * H_;// N0
    float* XS   = DINV + N0_;                // N0
    float* SCOR = XS + N0_;                  // N0
    float* EMF  = SCOR + N0_;                // E
    int*   SRC  = (int*)(EMF + E_);          // E
    int*   DST  = SRC + E_;                  // E
    int*   CNT  = DST + E_;                  // N0+1
    int*   OFF  = CNT + (N0_ + 1);           // N0+1
    int*   POS  = OFF + (N0_ + 1);           // N0
    int*   BSUM = POS + N0_;                 // 256
    int*   BSX  = BSUM + 256;                // 256
    int*   CSRC = BSX + 256;                 // E (CSR-ordered src ids)
    int*   PERM = CSRC + E_;                 // B*K1
    int*   REMAP= PERM + B_ * K1_;           // N0
    float* Z    = (float*)(REMAP + N0_);     // B*512
    float* Z1   = Z + B_ * 512;              // B*256
    float* Z2   = Z1 + B_ * 256;             // B*128

    auto cdiv = [](int a, int b) { return (a + b - 1) / b; };
    const int EB = E_ / 256;   // 3200

    init_edges_k<<<EB, 256, 0, stream>>>(esrc, edst, SRC, DST, EMF, CNT);

    const int nodes[4] = { N0_, B_ * K1_, B_ * K2_, B_ * K3_ };
    const int npgs[3]  = { NPG_, K1_, K2_ };
    const int ks[3]    = { K1_, K2_, K3_ };
    const float* Wm[3]  = { W1, W2, W3 };
    const float* bm[3]  = { b1, b2, b3 };
    const float* Wsm[3] = { Ws1, Ws2, Ws3 };
    const float* bsm[3] = { bs1, bs2, bs3 };

    for (int st = 0; st < 3; st++) {
        int n = nodes[st];
        int nNew = nodes[st + 1];
        int npg = npgs[st], k = ks[st];
        int nb = n / 256;

        // 1. xw = X @ W (128x128-tiled)
        if (st == 0)
            gemm128<<<dim3(n / 128, H_ / 128), 256, 0, stream>>>(x, Wm[st], XW, n, FIN_, H_);
        else
            gemm128<<<dim3(n / 128, H_ / 128), 256, 0, stream>>>(PH, Wm[st], XW, n, H_, H_);

        // 2. degree counts + CSR (CNT pre-zeroed by init/edge_remap)
        deg_count_k<<<EB, 256, 0, stream>>>(DST, EMF, CNT);
        scan1_k<<<nb, 256, 0, stream>>>(CNT, OFF, BSUM, DINV);
        scan2_k<<<1, 256, 0, stream>>>(BSUM, BSX, nb, OFF + n);
        scan3_k<<<nb, 256, 0, stream>>>(OFF, POS, BSX, REMAP, n);
        scatter_k<<<EB, 256, 0, stream>>>(SRC, DST, EMF, POS, CSRC);

        // 3. h = relu(agg + self + b)
        agg_gcn_k<<<n / 4, 256, 0, stream>>>(XW, OFF, CSRC, DINV, bm[st], Hb, n, 1);

        // 4. score GCN
        node_dot_k<<<n / 4, 256, 0, stream>>>(Hb, Wsm[st], XS, n);
        score_edge_k<<<cdiv(n, 256), 256, 0, stream>>>(XS, OFF, CSRC, DINV, bsm[st], SCOR, n);

        // 5. top-k per graph
        topk_k<<<B_, 256, 0, stream>>>(SCOR, npg, k, PERM, REMAP);

        // 6+7. pooled x + readout fused
        poolreadout_k<<<B_, 256, 0, stream>>>(Hb, SCOR, PERM, PH, Z, k, st > 0 ? 1 : 0);

        // 8. remap edges for next stage (+ zero CNT for next stage)
        edge_remap_k<<<EB, 256, 0, stream>>>(SRC, DST, EMF, REMAP, CNT, nNew);
    }

    // ---- MLP head ----
    gemm64<<<dim3(B_ / 64, 256 / 64), 256, 0, stream>>>(Z,  Wl1, bl1, Z1, B_, 512, 256, 1);
    gemm64<<<dim3(B_ / 64, 128 / 64), 256, 0, stream>>>(Z1, Wl2, bl2, Z2, B_, 256, 128, 1);
    mlp3_lsm_k<<<B_, 64, 0, stream>>>(Z2, Wl3, bl3, out);
}

// Round 4
// 428.963 us; speedup vs baseline: 2.0140x; 1.3496x over previous
//
#include <hip/hip_runtime.h>
#include <hip/hip_bf16.h>
#include <math.h>

#define B_   256
#define NPG_ 200
#define N0_  (B_*NPG_)     // 51200
#define DEGC 16
#define E_   (N0_*DEGC)    // 819200
#define FIN_ 128
#define H_   256
#define K1_  100
#define K2_  50
#define K3_  25

// bijective XCD-chunk swizzle (m204): dispatch round-robins block i -> XCD i%8;
// remap so XCD x owns a contiguous chunk of logical ids.
__device__ __forceinline__ int xcd_swz(int bid, int nwg) {
    int q = nwg >> 3, r = nwg & 7;
    int x = bid & 7, j = bid >> 3;
    return (x < r ? x * (q + 1) : r * (q + 1) + (x - r) * q) + j;
}

// ---------------- init: copy edges, em=1 ----------------
__global__ void init_edges_k(const int* __restrict__ es, const int* __restrict__ ed,
                             int* __restrict__ src, int* __restrict__ dst,
                             float* __restrict__ em) {
    int e = blockIdx.x * 256 + threadIdx.x;
    if (e < E_) { src[e] = es[e]; dst[e] = ed[e]; em[e] = 1.0f; }
}

// ---------------- gemm128: C[n x FO] = A[n x K] @ W[K x FO], 128x128 tile ----------------
__global__ __launch_bounds__(256) void gemm128(const float* __restrict__ A, const float* __restrict__ W,
                        float* __restrict__ C, int n, int K, int FO) {
    __shared__ float As[16][132];
    __shared__ float Bs[16][132];
    int t = threadIdx.x;
    int tx = t & 15, ty = t >> 4;
    int bm = xcd_swz(blockIdx.x, gridDim.x) * 128, bn = blockIdx.y * 128;
    int ar = t >> 1, akq = (t & 1) * 8;
    int bkk = t >> 4, bn0 = (t & 15) * 8;
    float acc[8][8] = {};
    for (int k0 = 0; k0 < K; k0 += 16) {
        float4 a0 = *(const float4*)&A[(size_t)(bm + ar) * K + k0 + akq];
        float4 a1 = *(const float4*)&A[(size_t)(bm + ar) * K + k0 + akq + 4];
        As[akq + 0][ar] = a0.x; As[akq + 1][ar] = a0.y; As[akq + 2][ar] = a0.z; As[akq + 3][ar] = a0.w;
        As[akq + 4][ar] = a1.x; As[akq + 5][ar] = a1.y; As[akq + 6][ar] = a1.z; As[akq + 7][ar] = a1.w;
        *(float4*)&Bs[bkk][bn0]     = *(const float4*)&W[(size_t)(k0 + bkk) * FO + bn + bn0];
        *(float4*)&Bs[bkk][bn0 + 4] = *(const float4*)&W[(size_t)(k0 + bkk) * FO + bn + bn0 + 4];
        __syncthreads();
        #pragma unroll
        for (int kk = 0; kk < 16; kk++) {
            float4 av0 = *(float4*)&As[kk][ty * 8];
            float4 av1 = *(float4*)&As[kk][ty * 8 + 4];
            float4 bv0 = *(float4*)&Bs[kk][tx * 8];
            float4 bv1 = *(float4*)&Bs[kk][tx * 8 + 4];
            float a[8] = {av0.x, av0.y, av0.z, av0.w, av1.x, av1.y, av1.z, av1.w};
            float b[8] = {bv0.x, bv0.y, bv0.z, bv0.w, bv1.x, bv1.y, bv1.z, bv1.w};
            #pragma unroll
            for (int i = 0; i < 8; i++)
                #pragma unroll
                for (int j = 0; j < 8; j++) acc[i][j] += a[i] * b[j];
        }
        __syncthreads();
    }
    #pragma unroll
    for (int i = 0; i < 8; i++) {
        float4 c0 = {acc[i][0], acc[i][1], acc[i][2], acc[i][3]};
        float4 c1 = {acc[i][4], acc[i][5], acc[i][6], acc[i][7]};
        *(float4*)&C[(size_t)(bm + ty * 8 + i) * FO + bn + tx * 8]     = c0;
        *(float4*)&C[(size_t)(bm + ty * 8 + i) * FO + bn + tx * 8 + 4] = c1;
    }
}

// ---------------- gemm64 (bias+relu) for MLP layers ----------------
__global__ void gemm64(const float* __restrict__ A, const float* __restrict__ W,
                       const float* __restrict__ bias, float* __restrict__ C,
                       int n, int K, int FO, int relu) {
    __shared__ float As[16][65];
    __shared__ float Bs[16][65];
    int tid = threadIdx.x;
    int tx = tid & 15, ty = tid >> 4;
    int bm = blockIdx.x * 64, bn = blockIdx.y * 64;
    float acc[4][4] = {};
    for (int k0 = 0; k0 < K; k0 += 16) {
        #pragma unroll
        for (int i = 0; i < 4; i++) {
            int lin = i * 256 + tid;
            int r = lin >> 4, kk = lin & 15;
            As[kk][r] = A[(size_t)(bm + r) * K + k0 + kk];
        }
        #pragma unroll
        for (int i = 0; i < 4; i++) {
            int lin = i * 256 + tid;
            int nn = lin & 63, kk = lin >> 6;
            Bs[kk][nn] = W[(size_t)(k0 + kk) * FO + bn + nn];
        }
        __syncthreads();
        #pragma unroll
        for (int kk = 0; kk < 16; kk++) {
            float a[4], b[4];
            #pragma unroll
            for (int i = 0; i < 4; i++) a[i] = As[kk][ty * 4 + i];
            #pragma unroll
            for (int j = 0; j < 4; j++) b[j] = Bs[kk][tx * 4 + j];
            #pragma unroll
            for (int i = 0; i < 4; i++)
                #pragma unroll
                for (int j = 0; j < 4; j++) acc[i][j] += a[i] * b[j];
        }
        __syncthreads();
    }
    for (int i = 0; i < 4; i++)
        for (int j = 0; j < 4; j++) {
            float v = acc[i][j] + bias[bn + tx * 4 + j];
            if (relu) v = fmaxf(v, 0.0f);
            C[(size_t)(bm + ty * 4 + i) * FO + bn + tx * 4 + j] = v;
        }
}

// ---------------- per-graph CSR build: one block per graph ----------------
// counts, exclusive scan, scatter — all in LDS. CSRC is padded per graph:
// graph g's slots are [g*npg*16, (g+1)*npg*16); OFFS/OFFE give per-node ranges.
__global__ void csr_build_k(const int* __restrict__ src, const int* __restrict__ dst,
                            const float* __restrict__ em, int* __restrict__ offs,
                            int* __restrict__ offe, int* __restrict__ csrc,
                            float* __restrict__ dinv, int npg) {
    __shared__ int cnt[256];
    __shared__ int pos[256];
    int g = xcd_swz(blockIdx.x, B_);
    int t = threadIdx.x;
    int ne = npg * DEGC;
    int base = g * ne, nb0 = g * npg;
    cnt[t] = 0;
    __syncthreads();
    for (int e = base + t; e < base + ne; e += 256)
        if (em[e] > 0.5f) atomicAdd(&cnt[dst[e] - nb0], 1);
    __syncthreads();
    int v = cnt[t];
    int s = v;
    // Hillis-Steele inclusive scan in LDS
    __shared__ int sc[256];
    sc[t] = s; __syncthreads();
    for (int d = 1; d < 256; d <<= 1) {
        int u = (t >= d) ? sc[t - d] : 0;
        __syncthreads();
        sc[t] += u;
        __syncthreads();
    }
    int excl = sc[t] - v;
    if (t < npg) {
        offs[nb0 + t] = base + excl;
        offe[nb0 + t] = base + excl + v;
        dinv[nb0 + t] = rsqrtf((float)v + 1.0f);
    }
    pos[t] = base + excl;
    __syncthreads();
    for (int e = base + t; e < base + ne; e += 256)
        if (em[e] > 0.5f) {
            int p = atomicAdd(&pos[dst[e] - nb0], 1);
            csrc[p] = src[e];
        }
}

// ---------------- GCN aggregation (wave/node) + fused score dot xs = h.Ws ----------------
__global__ void agg_gcn_k(const float* __restrict__ xw, const int* __restrict__ offs,
                          const int* __restrict__ offe, const int* __restrict__ csrc,
                          const float* __restrict__ dinv, const float* __restrict__ bias,
                          const float* __restrict__ Ws, float* __restrict__ out,
                          float* __restrict__ xs, int n) {
    int node = xcd_swz(blockIdx.x, gridDim.x) * 4 + (threadIdx.x >> 6);
    int lane = threadIdx.x & 63;
    const float4* xw4 = (const float4*)xw;
    float dd = dinv[node];
    float4 acc = {0.f, 0.f, 0.f, 0.f};
    int e0 = offs[node], e1 = offe[node];
    for (int j = e0; j < e1; j++) {
        int s = csrc[j];
        float c = dinv[s] * dd;
        float4 v = xw4[(size_t)s * 64 + lane];
        acc.x += c * v.x; acc.y += c * v.y; acc.z += c * v.z; acc.w += c * v.w;
    }
    float4 self = xw4[(size_t)node * 64 + lane];
    float scf = dd * dd;
    float4 r;
    r.x = fmaxf(acc.x + self.x * scf + bias[lane * 4 + 0], 0.f);
    r.y = fmaxf(acc.y + self.y * scf + bias[lane * 4 + 1], 0.f);
    r.z = fmaxf(acc.z + self.z * scf + bias[lane * 4 + 2], 0.f);
    r.w = fmaxf(acc.w + self.w * scf + bias[lane * 4 + 3], 0.f);
    ((float4*)out)[(size_t)node * 64 + lane] = r;
    // fused: xs[node] = h[node,:] . Ws
    float p = r.x * Ws[lane * 4 + 0] + r.y * Ws[lane * 4 + 1] +
              r.z * Ws[lane * 4 + 2] + r.w * Ws[lane * 4 + 3];
    #pragma unroll
    for (int d = 32; d > 0; d >>= 1) p += __shfl_down(p, d);
    if (lane == 0) xs[node] = p;
}

// ---------------- fused score GCN + top-k + pool + readout: one block per graph ----------------
__global__ void score_topk_pool_k(const float* __restrict__ h, const float* __restrict__ xs,
                                  const int* __restrict__ offs, const int* __restrict__ offe,
                                  const int* __restrict__ csrc, const float* __restrict__ dinv,
                                  const float* __restrict__ bs, int* __restrict__ remap,
                                  float* __restrict__ ph, float* __restrict__ z,
                                  int npg, int k, int accumulate) {
    __shared__ float xsl[256];
    __shared__ float sc[256];
    __shared__ int   id[256];
    __shared__ int   ps[128];
    __shared__ float ts[128];
    int g = xcd_swz(blockIdx.x, B_);
    int t = threadIdx.x;
    int nb0 = g * npg;
    // load local xs
    xsl[t] = (t < npg) ? xs[nb0 + t] : 0.f;
    __syncthreads();
    // score GCN over the (padded per-graph) CSR
    float scv = -INFINITY;
    if (t < npg) {
        int gi = nb0 + t;
        float dd = dinv[gi];
        float acc = 0.f;
        for (int j = offs[gi]; j < offe[gi]; j++) {
            int s = csrc[j];                 // global id, same graph
            acc += dinv[s] * xsl[s - nb0];
        }
        scv = acc * dd + xsl[t] * dd * dd + bs[0];
        remap[gi] = -1;
    }
    sc[t] = scv;
    id[t] = (t < npg) ? t : 0x7fffffff;
    __syncthreads();
    // bitonic sort by (-score, idx)
    for (int ksz = 2; ksz <= 256; ksz <<= 1) {
        for (int j = ksz >> 1; j > 0; j >>= 1) {
            int ixj = t ^ j;
            if (ixj > t) {
                float s1 = sc[t], s2 = sc[ixj];
                int i1 = id[t], i2 = id[ixj];
                bool asc = ((t & ksz) == 0);
                bool agtb = (s1 < s2) || (s1 == s2 && i1 > i2);
                if (asc ? agtb : !agtb) { sc[t] = s2; sc[ixj] = s1; id[t] = i2; id[ixj] = i1; }
            }
            __syncthreads();
        }
    }
    if (t < k) {
        remap[nb0 + id[t]] = g * k + t;
        ps[t] = nb0 + id[t];
        ts[t] = tanhf(sc[t]);
    }
    __syncthreads();
    // pool + readout: 256 threads = features
    float mx = -INFINITY, sm = 0.f;
    for (int j = 0; j < k; j++) {
        float v = h[(size_t)ps[j] * H_ + t] * ts[j];
        ph[(size_t)(g * k + j) * H_ + t] = v;
        mx = fmaxf(mx, v); sm += v;
    }
    float mean = sm / (float)k;
    if (accumulate) { z[g * 512 + t] += mx; z[g * 512 + 256 + t] += mean; }
    else            { z[g * 512 + t]  = mx; z[g * 512 + 256 + t]  = mean; }
}

// ---------------- edge remap ----------------
__global__ void edge_remap_k(int* __restrict__ src, int* __restrict__ dst,
                             float* __restrict__ em, const int* __restrict__ remap) {
    int e = blockIdx.x * 256 + threadIdx.x; if (e >= E_) return;
    int ns = remap[src[e]], nd = remap[dst[e]];
    float v = em[e];
    em[e] = (v > 0.5f && ns >= 0 && nd >= 0) ? 1.0f : 0.0f;
    src[e] = ns < 0 ? 0 : ns;
    dst[e] = nd < 0 ? 0 : nd;
}

// ---------------- fused MLP layer-3 + log_softmax ----------------
__global__ void mlp3_lsm_k(const float* __restrict__ A, const float* __restrict__ W,
                           const float* __restrict__ bias, float* __restrict__ out) {
    int m = blockIdx.x, l = threadIdx.x;   // 64 lanes, K=128
    float a0 = A[m * 128 + l], a1 = A[m * 128 + 64 + l];
    float r[10];
    #pragma unroll
    for (int n = 0; n < 10; n++) r[n] = a0 * W[l * 10 + n] + a1 * W[(l + 64) * 10 + n];
    #pragma unroll
    for (int d = 1; d < 64; d <<= 1)
        #pragma unroll
        for (int n = 0; n < 10; n++) r[n] += __shfl_xor(r[n], d);
    float v[10]; float mx = -INFINITY;
    #pragma unroll
    for (int n = 0; n < 10; n++) { v[n] = r[n] + bias[n]; mx = fmaxf(mx, v[n]); }
    float s = 0.f;
    #pragma unroll
    for (int n = 0; n < 10; n++) s += expf(v[n] - mx);
    float ls = logf(s);
    if (l < 10) out[m * 10 + l] = v[l] - mx - ls;
}

extern "C" void kernel_launch(void* const* d_in, const int* in_sizes, int n_in,
                              void* d_out, int out_size, void* d_ws, size_t ws_size,
                              hipStream_t stream) {
    const float* x   = (const float*)d_in[0];
    const int*  esrc = (const int*) d_in[1];
    const int*  edst = (const int*) d_in[2];
    const float *W1 = (const float*)d_in[3],  *b1 = (const float*)d_in[4];
    const float *Ws1= (const float*)d_in[5],  *bs1= (const float*)d_in[6];
    const float *W2 = (const float*)d_in[7],  *b2 = (const float*)d_in[8];
    const float *Ws2= (const float*)d_in[9],  *bs2= (const float*)d_in[10];
    const float *W3 = (const float*)d_in[11], *b3 = (const float*)d_in[12];
    const float *Ws3= (const float*)d_in[13], *bs3= (const float*)d_in[14];
    const float *Wl1= (const float*)d_in[15], *bl1= (const float*)d_in[16];
    const float *Wl2= (const float*)d_in[17], *bl2= (const float*)d_in[18];
    const float *Wl3= (const float*)d_in[19], *bl3= (const float*)d_in[20];
    float* out = (float*)d_out;

    // ---- workspace layout ----
    float* ws = (float*)d_ws;
    float* XW   = ws;                        // N0*H
    float* Hb   = XW + (size_t)N0_ * H_;     // N0*H
    float* PH   = Hb + (size_t)N0_ * H_;     // (B*K1)*H
    float* DINV = PH + (size_t)B_ * K1_ * H_;// N0
    float* XS   = DINV + N0_;                // N0
    float* EMF  = XS + N0_;                  // E
    int*   SRC  = (int*)(EMF + E_);          // E
    int*   DST  = SRC + E_;                  // E
    int*   OFFS = DST + E_;                  // N0
    int*   OFFE = OFFS + N0_;                // N0
    int*   CSRC = OFFE + N0_;                // E
    int*   REMAP= CSRC + E_;                 // N0
    float* Z    = (float*)(REMAP + N0_);     // B*512
    float* Z1   = Z + B_ * 512;              // B*256
    float* Z2   = Z1 + B_ * 256;             // B*128

    const int EB = E_ / 256;   // 3200

    init_edges_k<<<EB, 256, 0, stream>>>(esrc, edst, SRC, DST, EMF);

    const int nodes[4] = { N0_, B_ * K1_, B_ * K2_, B_ * K3_ };
    const int npgs[3]  = { NPG_, K1_, K2_ };
    const int ks[3]    = { K1_, K2_, K3_ };
    const float* Wm[3]  = { W1, W2, W3 };
    const float* bm[3]  = { b1, b2, b3 };
    const float* Wsm[3] = { Ws1, Ws2, Ws3 };
    const float* bsm[3] = { bs1, bs2, bs3 };

    for (int st = 0; st < 3; st++) {
        int n = nodes[st];
        int npg = npgs[st], k = ks[st];

        // 1. xw = X @ W (128x128-tiled, row panels XCD-chunked)
        if (st == 0)
            gemm128<<<dim3(n / 128, H_ / 128), 256, 0, stream>>>(x, Wm[st], XW, n, FIN_, H_);
        else
            gemm128<<<dim3(n / 128, H_ / 128), 256, 0, stream>>>(PH, Wm[st], XW, n, H_, H_);

        // 2. per-graph CSR build (counts+scan+scatter in LDS)
        csr_build_k<<<B_, 256, 0, stream>>>(SRC, DST, EMF, OFFS, OFFE, CSRC, DINV, npg);

        // 3. h = relu(agg + self + b), fused xs = h.Ws
        agg_gcn_k<<<n / 4, 256, 0, stream>>>(XW, OFFS, OFFE, CSRC, DINV, bm[st], Wsm[st], Hb, XS, n);

        // 4-7. score GCN + top-k + pool + readout (one block/graph)
        score_topk_pool_k<<<B_, 256, 0, stream>>>(Hb, XS, OFFS, OFFE, CSRC, DINV, bsm[st],
                                                  REMAP, PH, Z, npg, k, st > 0 ? 1 : 0);

        // 8. remap edges for next stage (not needed after last stage)
        if (st < 2)
            edge_remap_k<<<EB, 256, 0, stream>>>(SRC, DST, EMF, REMAP);
    }

    // ---- MLP head ----
    gemm64<<<dim3(B_ / 64, 256 / 64), 256, 0, stream>>>(Z,  Wl1, bl1, Z1, B_, 512, 256, 1);
    gemm64<<<dim3(B_ / 64, 128 / 64), 256, 0, stream>>>(Z1, Wl2, bl2, Z2, B_, 256, 128, 1);
    mlp3_lsm_k<<<B_, 64, 0, stream>>>(Z2, Wl3, bl3, out);
}